// Round 20
// baseline (345.236 us; speedup 1.0000x reference)
//
#include <hip/hip_runtime.h>
#include <hip/hip_bf16.h>

typedef __attribute__((ext_vector_type(8))) short short8;
typedef __attribute__((ext_vector_type(4))) float f32x4;
typedef __attribute__((ext_vector_type(16))) float f32x16;

#define DEV __device__ __forceinline__

DEV float bf2f(ushort u){ union { float f; unsigned int i; } x; x.i = ((unsigned int)u)<<16; return x.f; }
DEV ushort f2bf(float f){ union { float fl; unsigned int i; } x; x.fl = f; unsigned int r = x.i + 0x7fffu + ((x.i>>16)&1u); return (ushort)(r>>16); }

DEV void gl2lds16(const ushort* g, ushort* l){
  __builtin_amdgcn_global_load_lds((const __attribute__((address_space(1))) void*)g,
                                   (__attribute__((address_space(3))) void*)l, 16, 0, 0);
}
DEV f32x16 mfma32(short8 a, short8 b, f32x16 c){
  return __builtin_amdgcn_mfma_f32_32x32x16_bf16(a, b, c, 0, 0, 0);
}
DEV uint cvtpk(float lo, float hi){
  uint r; asm("v_cvt_pk_bf16_f32 %0, %1, %2" : "=v"(r) : "v"(lo), "v"(hi));
  return r;
}
DEV uint q8(float v){
  float c = fminf(fmaxf(v, -127.f), 127.f);
  return ((uint)(int)rintf(c)) & 255u;
}
// A&S 7.1.26 erf, |err| <= 1.5e-7
DEV float gelu_exact(float xx){
  float z = fabsf(xx) * 0.70710678118f;
  float tt = __builtin_amdgcn_rcpf(fmaf(0.3275911f, z, 1.f));
  float poly = fmaf(fmaf(fmaf(fmaf(1.061405429f, tt, -1.453152027f), tt, 1.421413741f),
                         tt, -0.284496736f), tt, 0.254829592f) * tt;
  float e = __builtin_amdgcn_exp2f(-z*z*1.4426950408f);
  float er = fmaf(-poly, e, 1.f);
  er = (xx < 0.f) ? -er : er;
  return 0.5f*xx*(1.f+er);
}

// ---------------- fp32 -> bf16 convert (Er only) ----------------
__global__ void cvt_f2b(const float* __restrict__ in, ushort* __restrict__ out, int n){
  int i = blockIdx.x*blockDim.x + threadIdx.x;
  int stride = gridDim.x*blockDim.x;
  for (; i < n; i += stride) out[i] = f2bf(in[i]);
}

// ---------------- fp32 [K][N] -> bf16 [N][K+pad] tiled transpose ----------------
__global__ __launch_bounds__(256) void wt_cvt(const float* __restrict__ in, ushort* __restrict__ out,
                                              int K, int N, int ldk){
  const int n0 = blockIdx.x*64, k0 = blockIdx.y*64;
  __shared__ float T[64][65];
  const int tid = threadIdx.x;
  const int r = tid>>4, c = (tid&15)*4;
  #pragma unroll
  for (int p=0;p<4;p++){
    float4 v = *(const float4*)&in[(size_t)(k0 + p*16 + r)*N + n0 + c];
    T[p*16+r][c+0]=v.x; T[p*16+r][c+1]=v.y; T[p*16+r][c+2]=v.z; T[p*16+r][c+3]=v.w;
  }
  __syncthreads();
  #pragma unroll
  for (int p=0;p<4;p++){
    int n = p*16 + r;
    ushort u0 = f2bf(T[c+0][n]), u1 = f2bf(T[c+1][n]), u2 = f2bf(T[c+2][n]), u3 = f2bf(T[c+3][n]);
    ushort4 u = make_ushort4(u0,u1,u2,u3);
    *(ushort4*)&out[(size_t)(n0+n)*ldk + k0 + c] = u;
  }
}

// ---------------- V transpose ----------------
__global__ __launch_bounds__(256) void vt_k(const ushort* __restrict__ qkv, ushort* __restrict__ vt){
  const int bh = blockIdx.y; const int b = bh>>4, h = bh&15;
  const int n0 = blockIdx.x*64;
  __shared__ ushort T[64][66];
  const int tid = threadIdx.x;
  const int r = tid>>3, c8 = (tid&7)*8;
  #pragma unroll
  for (int p=0;p<2;p++){
    int row = p*32 + r;
    short8 v = *(const short8*)&qkv[(size_t)(b*1024 + n0 + row)*3200 + 2048 + h*64 + c8];
    #pragma unroll
    for (int i=0;i<8;i++) T[row][c8+i] = ((ushort*)&v)[i];
  }
  __syncthreads();
  #pragma unroll
  for (int p=0;p<2;p++){
    int d = p*32 + r;
    union { ushort u[8]; short8 v; } o;
    #pragma unroll
    for (int i=0;i<8;i++) o.u[i] = T[c8+i][d];
    *(short8*)&vt[(size_t)(bh*64 + d)*1152 + n0 + c8] = o.v;
  }
}

// ---------------- LayerNorm over C=1024 ----------------
__global__ __launch_bounds__(256) void ln_rows(const float* __restrict__ in,
                                               const float* __restrict__ g,
                                               const float* __restrict__ bta,
                                               ushort* __restrict__ out, int ldo){
  int row = blockIdx.x; int tid = threadIdx.x;
  const float* x = in + (size_t)row*1024;
  float v[4]; float s = 0.f;
  #pragma unroll
  for (int i=0;i<4;i++){ v[i] = x[tid + 256*i]; s += v[i]; }
  __shared__ float rbuf[256];
  rbuf[tid] = s; __syncthreads();
  for (int off=128; off>0; off>>=1){ if (tid<off) rbuf[tid]+=rbuf[tid+off]; __syncthreads(); }
  float mean = rbuf[0] * (1.f/1024.f);
  __syncthreads();
  float s2 = 0.f;
  #pragma unroll
  for (int i=0;i<4;i++){ float d=v[i]-mean; s2 += d*d; }
  rbuf[tid] = s2; __syncthreads();
  for (int off=128; off>0; off>>=1){ if (tid<off) rbuf[tid]+=rbuf[tid+off]; __syncthreads(); }
  float var = rbuf[0] * (1.f/1024.f);
  float rstd = rsqrtf(var + 1e-5f);
  #pragma unroll
  for (int i=0;i<4;i++){ int c = tid+256*i; out[(size_t)row*ldo+c] = f2bf((v[i]-mean)*rstd*g[c]+bta[c]); }
}

// ---------------- time-embedding GEMM ----------------
__global__ __launch_bounds__(256) void tq_gemm2(const float* __restrict__ t, const float* __restrict__ tw,
                                                const float* __restrict__ tb, float* __restrict__ tq){
  const int tid = threadIdx.x;
  const int j = blockIdx.x*64 + (tid & 63);
  const int sl = tid >> 6;
  float acc[4] = {0.f,0.f,0.f,0.f};
  for (int k = sl*64; k < sl*64+64; ++k){
    float wv = tw[(size_t)k*3072 + j];
    #pragma unroll
    for (int b=0;b<4;b++) acc[b] = fmaf(t[b*256+k], wv, acc[b]);
  }
  __shared__ float red[4][4][64];
  #pragma unroll
  for (int b=0;b<4;b++) red[sl][b][tid&63] = acc[b];
  __syncthreads();
  if (sl == 0){
    #pragma unroll
    for (int b=0;b<4;b++)
      tq[b*3072 + j] = red[0][b][tid&63] + red[1][b][tid&63] + red[2][b][tid&63] + red[3][b][tid&63] + tb[j];
  }
}

// ---------------- gemm9: 128xTN, BK=32, 3-slot counted-vmcnt pipeline + 4x4 raster ----------
// EPI 0: bf16 = acc + bias + tqkv ; EPI 1: f32 = acc + bias + extra ; EPI 2: bf16 = gelu(acc+bias)
// EPI 3: SPLIT-K partial — sk = swz&1 selects K-half; raw f32 acc -> outf (+sk*4M), no bias.
template<int EPI, int TN>
__global__ __launch_bounds__(256) void gemm9(
    const ushort* __restrict__ A, const ushort* __restrict__ Bt,
    const float* __restrict__ bias, const float* __restrict__ extra,
    ushort* __restrict__ outb, float* __restrict__ outf,
    int K, int lda, int ldb, int ldo, int lde, int nbx)
{
  constexpr int NJ = TN/32;
  __shared__ __align__(16) ushort Al[3][128*32];
  __shared__ __align__(16) ushort Bl[3][TN*32];
  const int nwg = gridDim.x, cpx = nwg >> 3;
  const int bid = blockIdx.x;
  int swz = (bid & 7)*cpx + (bid >> 3);
  if constexpr (EPI==3){
    const int sk = swz & 1;
    swz >>= 1;
    A   += (size_t)sk * K;
    Bt  += (size_t)sk * K;
    outf += (size_t)sk * 4194304;
  }
  const int rowblk = swz / (nbx*4);
  const int lo2 = swz % (nbx*4);
  const int grp = lo2 >> 4;
  const int ir = (lo2 >> 2) & 3, ic = lo2 & 3;
  const int m0 = (rowblk*4 + ir)*128;
  const int n0 = (grp*4 + ic)*TN;
  const int tid = threadIdx.x, lane = tid & 63, wid = tid >> 6;
  const int wm = (wid&1)*64, wn = (wid>>1)*(TN/2);
  const int l15 = lane&15, l4 = lane>>4;
  f32x4 acc[4][NJ];
  #pragma unroll
  for (int i=0;i<4;i++)
    #pragma unroll
    for (int jx=0;jx<NJ;jx++){ acc[i][jx][0]=0.f; acc[i][jx][1]=0.f; acc[i][jx][2]=0.f; acc[i][jx][3]=0.f; }
  const ushort* a0p = A + (size_t)(m0 + (tid>>2))*lda + (tid&3)*8;
  const ushort* a1p = A + (size_t)(m0 + 64 + (tid>>2))*lda + (tid&3)*8;
  const ushort* b0p = Bt + (size_t)(n0 + (tid>>2))*ldb + (tid&3)*8;
  const ushort* b1p = nullptr;
  if constexpr (TN==128) b1p = Bt + (size_t)(n0 + 64 + (tid>>2))*ldb + (tid&3)*8;
  const int lsl = tid*8, lsh = (tid+256)*8;

  auto stage = [&](int s, int k1){
    gl2lds16(a0p + k1, &Al[s][lsl]);
    gl2lds16(a1p + k1, &Al[s][lsh]);
    gl2lds16(b0p + k1, &Bl[s][lsl]);
    if constexpr (TN==128) gl2lds16(b1p + k1, &Bl[s][lsh]);
  };

  const int nk = K >> 5;
  stage(0, 0);
  stage(1, 32);
  int s = 0;
  for (int it=0; it<nk; ++it){
    if constexpr (TN==128)
      asm volatile("s_waitcnt vmcnt(4) lgkmcnt(0)" ::: "memory");
    else
      asm volatile("s_waitcnt vmcnt(3) lgkmcnt(0)" ::: "memory");
    __builtin_amdgcn_sched_barrier(0);
    __builtin_amdgcn_s_barrier();
    if (it+2 < nk){
      int s2 = s + 2; if (s2 >= 3) s2 -= 3;
      stage(s2, (it+2) << 5);
    }
    ushort* Ac = Al[s];  ushort* Bc = Bl[s];
    short8 af[4], bfr[NJ];
    #pragma unroll
    for (int mi=0;mi<4;mi++) af[mi]  = *(const short8*)&Ac[(wm + mi*16 + l15)*32 + l4*8];
    #pragma unroll
    for (int nj=0;nj<NJ;nj++) bfr[nj] = *(const short8*)&Bc[(wn + nj*16 + l15)*32 + l4*8];
    #pragma unroll
    for (int mi=0;mi<4;mi++)
      #pragma unroll
      for (int nj=0;nj<NJ;nj++)
        acc[mi][nj] = __builtin_amdgcn_mfma_f32_16x16x32_bf16(af[mi], bfr[nj], acc[mi][nj], 0,0,0);
    if (++s >= 3) s = 0;
  }
  #pragma unroll
  for (int mi=0;mi<4;mi++)
    #pragma unroll
    for (int nj=0;nj<NJ;nj++)
      #pragma unroll
      for (int j=0;j<4;j++){
        int row = m0 + wm + mi*16 + l4*4 + j;
        int col = n0 + wn + nj*16 + l15;
        if constexpr (EPI==3){
          outf[(size_t)row*ldo+col] = acc[mi][nj][j];
        } else {
          float v = acc[mi][nj][j] + bias[col];
          if constexpr (EPI==0){ v += extra[(size_t)(row>>10)*lde + col]; outb[(size_t)row*ldo+col] = f2bf(v); }
          else if constexpr (EPI==1){ v += extra[(size_t)row*lde + col]; outf[(size_t)row*ldo+col] = v; }
          else { outb[(size_t)row*ldo+col] = f2bf(gelu_exact(v)); }
        }
      }
}

// ---------------- ff2_merge: o = p0 + p1 + bias[col] + o  (deterministic split-K reduce) -------
__global__ __launch_bounds__(256) void ff2_merge(const float* __restrict__ part,
                                                 const float* __restrict__ bias,
                                                 float* __restrict__ o){
  const int i = (blockIdx.x*256 + threadIdx.x)*8;
  const int col = i & 1023;
  float4 a0 = *(const float4*)(part + i);
  float4 a1 = *(const float4*)(part + i + 4);
  float4 b0 = *(const float4*)(part + 4194304 + i);
  float4 b1 = *(const float4*)(part + 4194304 + i + 4);
  float4 o0 = *(const float4*)(o + i);
  float4 o1 = *(const float4*)(o + i + 4);
  float4 c0 = *(const float4*)(bias + col);
  float4 c1 = *(const float4*)(bias + col + 4);
  o0.x += a0.x + b0.x + c0.x; o0.y += a0.y + b0.y + c0.y;
  o0.z += a0.z + b0.z + c0.z; o0.w += a0.w + b0.w + c0.w;
  o1.x += a1.x + b1.x + c1.x; o1.y += a1.y + b1.y + c1.y;
  o1.z += a1.z + b1.z + c1.z; o1.w += a1.w + b1.w + c1.w;
  *(float4*)(o + i) = o0;
  *(float4*)(o + i + 4) = o1;
}

// ---------------- relskew8_v5: tiled int8 skew, COALESCED uint4 dump ----------------
__global__ __launch_bounds__(256) void relskew8_v5(
    const ushort* __restrict__ qkv, const ushort* __restrict__ Er,
    signed char* __restrict__ srelT)
{
  const int bid0 = blockIdx.x;
  const int swz = (bid0 & 7)*256 + (bid0 >> 3);
  const int bh = swz >> 5, b = bh >> 4, h = bh & 15;
  const int r0 = (swz & 31)*32;
  const int tid = threadIdx.x, w = tid >> 6, lane = tid & 63;
  const int l31 = lane & 31, hi = lane >> 5;

  __shared__ signed char T8[33*1044];
  signed char* srb = srelT + (size_t)bh*32*32*1024;

  if (tid < 33){
    int tgt = r0 - 1 + tid;
    int c = tgt + 1;
    if (tgt >= 0 && c <= 1023) T8[tid*1044 + c] = 0;
  }

  const ushort* Qp = qkv + (size_t)b*1024*3200 + h*64;
  const int r = r0 + l31;
  short8 qf0 = *(const short8*)(Qp + (size_t)r*3200 +      hi*8);
  short8 qf1 = *(const short8*)(Qp + (size_t)r*3200 + 16 + hi*8);
  short8 qf2 = *(const short8*)(Qp + (size_t)r*3200 + 32 + hi*8);
  short8 qf3 = *(const short8*)(Qp + (size_t)r*3200 + 48 + hi*8);

  const float ESC = 92.332481f;
  for (int t=0; t<8; ++t){
    const int e0 = w*256 + t*32;
    const ushort* ep = Er + (size_t)(e0 + l31)*64 + hi*8;
    short8 ea0 = *(const short8*)(ep);
    short8 ea1 = *(const short8*)(ep + 16);
    short8 ea2 = *(const short8*)(ep + 32);
    short8 ea3 = *(const short8*)(ep + 48);
    f32x16 acc = {};
    acc = mfma32(ea0, qf0, acc);
    acc = mfma32(ea1, qf1, acc);
    acc = mfma32(ea2, qf2, acc);
    acc = mfma32(ea3, qf3, acc);
    #pragma unroll
    for (int q=0;q<4;q++)
      #pragma unroll
      for (int j=0;j<4;j++){
        int e = e0 + 8*q + 4*hi + j;
        signed char v = (signed char)(int)q8(acc[4*q+j]*ESC);
        bool below = (e + r) >= 1023;
        int i = below ? (l31 + 1) : l31;
        int c = e + r + (below ? -1023 : 1);
        T8[i*1044 + c] = v;
      }
  }
  __syncthreads();

  const int rt = r0 >> 5;
  const bool lastfull = (r0 == 992);
  signed char* base = srb + (size_t)rt*32768;
  #pragma unroll
  for (int p=0; p<8; ++p){
    int off = p*4096 + tid*16;
    int ct = off >> 10;
    int wi = off & 1023;
    int row = wi >> 5;
    int sh = wi & 31;
    int i = row + 1;
    int g0 = sh ? 4 : 0;
    const signed char* src = T8 + i*1044 + ct*32;
    uint4 u;
    u.x = *(const uint*)(src + g0);
    u.y = *(const uint*)(src + g0 + 8);
    u.z = *(const uint*)(src + g0 + 16);
    u.w = *(const uint*)(src + g0 + 24);
    if (row < 31 || lastfull){
      *(uint4*)(base + off) = u;
    } else if (ct <= rt){
      *(uint4*)(base + off) = u;
    } else if (ct == rt+1 && sh == 0){
      base[off] = ((const signed char*)&u)[0];
    }
  }
  if (r0 > 0 && tid < 64){
    int ct = tid >> 1, sh = (tid & 1)*16;
    int g0 = sh ? 4 : 0;
    const signed char* src = T8 + ct*32;
    signed char* tbase = srb + ((size_t)(rt-1)*32 + ct)*1024 + 31*32 + sh;
    if (ct > rt || (ct == rt && sh == 16)){
      uint4 u;
      u.x = *(const uint*)(src + g0);
      u.y = *(const uint*)(src + g0 + 8);
      u.z = *(const uint*)(src + g0 + 16);
      u.w = *(const uint*)(src + g0 + 24);
      *(uint4*)tbase = u;
    } else if (ct == rt && sh == 0){
      #pragma unroll
      for (int s2=1; s2<16; ++s2){
        int col = (s2>>2)*8 + (s2&3);
        tbase[s2] = src[col];
      }
    }
  }
}

// ---------------- attn11: 32x32 flash, ONE uint4 tiled bias load/step ----------------
__global__ __launch_bounds__(256) void attn11(
    const ushort* __restrict__ qkv, const signed char* __restrict__ srelT,
    const ushort* __restrict__ Vt, ushort* __restrict__ out)
{
  const int bid0 = blockIdx.x;
  const int swz = (bid0 & 7)*64 + (bid0 >> 3);
  const int bh = swz >> 3, b = bh >> 4, h = bh & 15;
  const int rblk = (swz & 7)*128;
  const int tid = threadIdx.x, w = tid >> 6, lane = tid & 63;
  const int l31 = lane & 31, hi = lane >> 5;
  const int r = rblk + w*32 + l31;
  const ushort* Qp = qkv + (size_t)b*1024*3200 + h*64;
  const ushort* Kp = Qp + 1024;
  const ushort* Vp = Vt + (size_t)bh*64*1152;
  const signed char* BpT = srelT + ((size_t)bh*32 + (r>>5))*32*1024 + (r&31)*32 + hi*16;

  short8 qf0 = *(const short8*)(Qp + (size_t)r*3200 +      hi*8);
  short8 qf1 = *(const short8*)(Qp + (size_t)r*3200 + 16 + hi*8);
  short8 qf2 = *(const short8*)(Qp + (size_t)r*3200 + 32 + hi*8);
  short8 qf3 = *(const short8*)(Qp + (size_t)r*3200 + 48 + hi*8);

  f32x16 O0 = {}, O1 = {};
  float lsum = 0.f;

  short8 kA0 = *(const short8*)(Kp + (size_t)l31*3200 +      hi*8);
  short8 kA1 = *(const short8*)(Kp + (size_t)l31*3200 + 16 + hi*8);
  short8 kA2 = *(const short8*)(Kp + (size_t)l31*3200 + 32 + hi*8);
  short8 kA3 = *(const short8*)(Kp + (size_t)l31*3200 + 48 + hi*8);
  short8 kB0, kB1, kB2, kB3;

  auto step = [&](short8& ka0, short8& ka1, short8& ka2, short8& ka3,
                  short8& kn0, short8& kn1, short8& kn2, short8& kn3, int t){
    const int c0 = t*32;
    if (t < 31){
      const ushort* kp = Kp + (size_t)(c0 + 32 + l31)*3200 + hi*8;
      kn0 = *(const short8*)(kp);
      kn1 = *(const short8*)(kp + 16);
      kn2 = *(const short8*)(kp + 32);
      kn3 = *(const short8*)(kp + 48);
    }
    uint4 bw = *(const uint4*)(BpT + (size_t)t*1024);
    const signed char* bb = (const signed char*)&bw;
    short8 v00 = *(const short8*)(Vp + (size_t)l31*1152      + c0 +      hi*8);
    short8 v01 = *(const short8*)(Vp + (size_t)l31*1152      + c0 + 16 + hi*8);
    short8 v10 = *(const short8*)(Vp + (size_t)(32+l31)*1152 + c0 +      hi*8);
    short8 v11 = *(const short8*)(Vp + (size_t)(32+l31)*1152 + c0 + 16 + hi*8);
    f32x16 S = {};
    __builtin_amdgcn_s_setprio(1);
    S = mfma32(ka0, qf0, S);
    S = mfma32(ka1, qf1, S);
    S = mfma32(ka2, qf2, S);
    S = mfma32(ka3, qf3, S);
    __builtin_amdgcn_s_setprio(0);
    float p[16];
    float s0=0.f, s1=0.f, s2=0.f, s3=0.f;
    #pragma unroll
    for (int i=0;i<16;i++){
      float pv = __builtin_amdgcn_exp2f(fmaf(S[i], 0.18033688f, (float)bb[i]*0.015625f));
      p[i] = pv;
      if ((i&3)==0) s0 += pv; else if ((i&3)==1) s1 += pv;
      else if ((i&3)==2) s2 += pv; else s3 += pv;
    }
    lsum += (s0+s1)+(s2+s3);
    uint W00=cvtpk(p[0],p[1]),   W01=cvtpk(p[2],p[3]);
    uint W10=cvtpk(p[4],p[5]),   W11=cvtpk(p[6],p[7]);
    uint W20=cvtpk(p[8],p[9]),   W21=cvtpk(p[10],p[11]);
    uint W30=cvtpk(p[12],p[13]), W31=cvtpk(p[14],p[15]);
    uint x00 = (uint)__shfl_xor((int)(hi? W00 : W10), 32, 64);
    uint x01 = (uint)__shfl_xor((int)(hi? W01 : W11), 32, 64);
    uint x10 = (uint)__shfl_xor((int)(hi? W20 : W30), 32, 64);
    uint x11 = (uint)__shfl_xor((int)(hi? W21 : W31), 32, 64);
    union { uint u[4]; short8 v; } pf0, pf1;
    pf0.u[0] = hi ? x00 : W00;  pf0.u[1] = hi ? x01 : W01;
    pf0.u[2] = hi ? W10 : x00;  pf0.u[3] = hi ? W11 : x01;
    pf1.u[0] = hi ? x10 : W20;  pf1.u[1] = hi ? x11 : W21;
    pf1.u[2] = hi ? W30 : x10;  pf1.u[3] = hi ? W31 : x11;
    __builtin_amdgcn_s_setprio(1);
    O0 = mfma32(v00, pf0.v, O0);
    O0 = mfma32(v01, pf1.v, O0);
    O1 = mfma32(v10, pf0.v, O1);
    O1 = mfma32(v11, pf1.v, O1);
    __builtin_amdgcn_s_setprio(0);
  };
  for (int t=0;t<32;t+=2){
    step(kA0,kA1,kA2,kA3, kB0,kB1,kB2,kB3, t);
    step(kB0,kB1,kB2,kB3, kA0,kA1,kA2,kA3, t+1);
  }
  float inv = 1.f/(lsum + __shfl_xor(lsum, 32, 64));
  ushort* op = out + ((size_t)(b*1024 + r))*1152 + h*64;
  #pragma unroll
  for (int rq=0;rq<4;rq++)
    #pragma unroll
    for (int s=0;s<2;s++){
      int reg = rq*4 + s*2;
      uint w0 = cvtpk(O0[reg]*inv, O0[reg+1]*inv);
      uint w1 = cvtpk(O1[reg]*inv, O1[reg+1]*inv);
      int d = rq*8 + hi*4 + s*2;
      *(uint*)(op + d) = w0;
      *(uint*)(op + 32 + d) = w1;
    }
}

extern "C" void kernel_launch(void* const* d_in, const int* in_sizes, int n_in,
                              void* d_out, int out_size, void* d_ws, size_t ws_size,
                              hipStream_t stream)
{
  const float* x    = (const float*)d_in[0];
  const float* t    = (const float*)d_in[1];
  const float* ln1g = (const float*)d_in[2];
  const float* ln1b = (const float*)d_in[3];
  const float* qkvw = (const float*)d_in[4];
  const float* qkvb = (const float*)d_in[5];
  const float* timew= (const float*)d_in[6];
  const float* timeb= (const float*)d_in[7];
  const float* outw = (const float*)d_in[8];
  const float* outbv= (const float*)d_in[9];
  const float* Er   = (const float*)d_in[10];
  const float* ln2g = (const float*)d_in[11];
  const float* ln2b = (const float*)d_in[12];
  const float* ff1w = (const float*)d_in[13];
  const float* ff1b = (const float*)d_in[14];
  const float* ff2w = (const float*)d_in[15];
  const float* ff2b = (const float*)d_in[16];
  float* o = (float*)d_out;

  char* ws = (char*)d_ws;
  ushort* qkvw_t = (ushort*)(ws);              // [3072][1152]
  ushort* outw_t = (ushort*)(ws + 7077888);    // [1024][1152]
  ushort* ff1w_t = (ushort*)(ws + 9437184);    // [4096][1152]
  ushort* ff2w_t = (ushort*)(ws + 18874368);   // [1024][4224]
  ushort* er_b   = (ushort*)(ws + 27525120);   // [1024][64]
  float*  tq     = (float*) (ws + 27656192);   // [4][3072]
  ushort* bufA   = (ushort*)(ws + 27705344);   // [4096][1152]
  ushort* vt     = (ushort*)(ws + 37142528);   // [4096][1152]
  ushort* bufB   = (ushort*)(ws + 46579712);   // [4096][4224] (qkv at stride 3200 / ff1o at 4224)
  signed char* srelT = (signed char*)(ws + 81182720);  // [64][32][32][1024] tiled int8 (67.1 MB)
  float* part    = (float*)(ws + 150994944);   // [2][4096][1024] f32 split-K partials (33.6 MB)

  wt_cvt<<<dim3(48,16),256,0,stream>>>(qkvw, qkvw_t, 1024, 3072, 1152);
  wt_cvt<<<dim3(16,16),256,0,stream>>>(outw, outw_t, 1024, 1024, 1152);
  wt_cvt<<<dim3(64,16),256,0,stream>>>(ff1w, ff1w_t, 1024, 4096, 1152);
  wt_cvt<<<dim3(16,64),256,0,stream>>>(ff2w, ff2w_t, 4096, 1024, 4224);
  cvt_f2b<<<256,256,0,stream>>>(Er, er_b, 65536);

  ln_rows<<<4096,256,0,stream>>>(x, ln1g, ln1b, bufA, 1152);
  tq_gemm2<<<48,256,0,stream>>>(t, timew, timeb, tq);
  gemm9<0,128><<<768,256,0,stream>>>(bufA, qkvw_t, qkvb, tq, bufB, nullptr,
                                     1024, 1152, 1152, 3200, 3072, 24);
  vt_k<<<dim3(16,64),256,0,stream>>>(bufB, vt);
  relskew8_v5<<<2048,256,0,stream>>>(bufB, er_b, srelT);
  attn11<<<512,256,0,stream>>>(bufB, srelT, vt, bufA);
  gemm9<1,64><<<512,256,0,stream>>>(bufA, outw_t, outbv, x, nullptr, o,
                                    1024, 1152, 1152, 1024, 1024, 16);
  ln_rows<<<4096,256,0,stream>>>(o, ln2g, ln2b, bufA, 1152);
  gemm9<2,128><<<1024,256,0,stream>>>(bufA, ff1w_t, ff1b, nullptr, bufB, nullptr,
                                      1024, 1152, 1152, 4224, 0, 32);
  // FF2 split-K=2: 1024 WGs (4/CU), halves write f32 partials; deterministic merge adds bias+residual
  gemm9<3,64><<<1024,256,0,stream>>>(bufB, ff2w_t, nullptr, nullptr, nullptr, part,
                                     2048, 4224, 4224, 1024, 0, 16);
  ff2_merge<<<2048,256,0,stream>>>(part, ff2b, o);
}

// Round 21
// 342.374 us; speedup vs baseline: 1.0084x; 1.0084x over previous
//
#include <hip/hip_runtime.h>
#include <hip/hip_bf16.h>

typedef __attribute__((ext_vector_type(8))) short short8;
typedef __attribute__((ext_vector_type(4))) float f32x4;
typedef __attribute__((ext_vector_type(16))) float f32x16;

#define DEV __device__ __forceinline__

DEV float bf2f(ushort u){ union { float f; unsigned int i; } x; x.i = ((unsigned int)u)<<16; return x.f; }
DEV ushort f2bf(float f){ union { float fl; unsigned int i; } x; x.fl = f; unsigned int r = x.i + 0x7fffu + ((x.i>>16)&1u); return (ushort)(r>>16); }

DEV void gl2lds16(const ushort* g, ushort* l){
  __builtin_amdgcn_global_load_lds((const __attribute__((address_space(1))) void*)g,
                                   (__attribute__((address_space(3))) void*)l, 16, 0, 0);
}
DEV f32x16 mfma32(short8 a, short8 b, f32x16 c){
  return __builtin_amdgcn_mfma_f32_32x32x16_bf16(a, b, c, 0, 0, 0);
}
DEV uint cvtpk(float lo, float hi){
  uint r; asm("v_cvt_pk_bf16_f32 %0, %1, %2" : "=v"(r) : "v"(lo), "v"(hi));
  return r;
}
DEV uint q8(float v){
  float c = fminf(fmaxf(v, -127.f), 127.f);
  return ((uint)(int)rintf(c)) & 255u;
}
// A&S 7.1.26 erf, |err| <= 1.5e-7
DEV float gelu_exact(float xx){
  float z = fabsf(xx) * 0.70710678118f;
  float tt = __builtin_amdgcn_rcpf(fmaf(0.3275911f, z, 1.f));
  float poly = fmaf(fmaf(fmaf(fmaf(1.061405429f, tt, -1.453152027f), tt, 1.421413741f),
                         tt, -0.284496736f), tt, 0.254829592f) * tt;
  float e = __builtin_amdgcn_exp2f(-z*z*1.4426950408f);
  float er = fmaf(-poly, e, 1.f);
  er = (xx < 0.f) ? -er : er;
  return 0.5f*xx*(1.f+er);
}

// ---------------- fp32 -> bf16 convert (Er only) ----------------
__global__ void cvt_f2b(const float* __restrict__ in, ushort* __restrict__ out, int n){
  int i = blockIdx.x*blockDim.x + threadIdx.x;
  int stride = gridDim.x*blockDim.x;
  for (; i < n; i += stride) out[i] = f2bf(in[i]);
}

// ---------------- fp32 [K][N] -> bf16 [N][K+pad] tiled transpose ----------------
__global__ __launch_bounds__(256) void wt_cvt(const float* __restrict__ in, ushort* __restrict__ out,
                                              int K, int N, int ldk){
  const int n0 = blockIdx.x*64, k0 = blockIdx.y*64;
  __shared__ float T[64][65];
  const int tid = threadIdx.x;
  const int r = tid>>4, c = (tid&15)*4;
  #pragma unroll
  for (int p=0;p<4;p++){
    float4 v = *(const float4*)&in[(size_t)(k0 + p*16 + r)*N + n0 + c];
    T[p*16+r][c+0]=v.x; T[p*16+r][c+1]=v.y; T[p*16+r][c+2]=v.z; T[p*16+r][c+3]=v.w;
  }
  __syncthreads();
  #pragma unroll
  for (int p=0;p<4;p++){
    int n = p*16 + r;
    ushort u0 = f2bf(T[c+0][n]), u1 = f2bf(T[c+1][n]), u2 = f2bf(T[c+2][n]), u3 = f2bf(T[c+3][n]);
    ushort4 u = make_ushort4(u0,u1,u2,u3);
    *(ushort4*)&out[(size_t)(n0+n)*ldk + k0 + c] = u;
  }
}

// ---------------- V transpose ----------------
__global__ __launch_bounds__(256) void vt_k(const ushort* __restrict__ qkv, ushort* __restrict__ vt){
  const int bh = blockIdx.y; const int b = bh>>4, h = bh&15;
  const int n0 = blockIdx.x*64;
  __shared__ ushort T[64][66];
  const int tid = threadIdx.x;
  const int r = tid>>3, c8 = (tid&7)*8;
  #pragma unroll
  for (int p=0;p<2;p++){
    int row = p*32 + r;
    short8 v = *(const short8*)&qkv[(size_t)(b*1024 + n0 + row)*3200 + 2048 + h*64 + c8];
    #pragma unroll
    for (int i=0;i<8;i++) T[row][c8+i] = ((ushort*)&v)[i];
  }
  __syncthreads();
  #pragma unroll
  for (int p=0;p<2;p++){
    int d = p*32 + r;
    union { ushort u[8]; short8 v; } o;
    #pragma unroll
    for (int i=0;i<8;i++) o.u[i] = T[c8+i][d];
    *(short8*)&vt[(size_t)(bh*64 + d)*1152 + n0 + c8] = o.v;
  }
}

// ---------------- LayerNorm over C=1024 ----------------
__global__ __launch_bounds__(256) void ln_rows(const float* __restrict__ in,
                                               const float* __restrict__ g,
                                               const float* __restrict__ bta,
                                               ushort* __restrict__ out, int ldo){
  int row = blockIdx.x; int tid = threadIdx.x;
  const float* x = in + (size_t)row*1024;
  float v[4]; float s = 0.f;
  #pragma unroll
  for (int i=0;i<4;i++){ v[i] = x[tid + 256*i]; s += v[i]; }
  __shared__ float rbuf[256];
  rbuf[tid] = s; __syncthreads();
  for (int off=128; off>0; off>>=1){ if (tid<off) rbuf[tid]+=rbuf[tid+off]; __syncthreads(); }
  float mean = rbuf[0] * (1.f/1024.f);
  __syncthreads();
  float s2 = 0.f;
  #pragma unroll
  for (int i=0;i<4;i++){ float d=v[i]-mean; s2 += d*d; }
  rbuf[tid] = s2; __syncthreads();
  for (int off=128; off>0; off>>=1){ if (tid<off) rbuf[tid]+=rbuf[tid+off]; __syncthreads(); }
  float var = rbuf[0] * (1.f/1024.f);
  float rstd = rsqrtf(var + 1e-5f);
  #pragma unroll
  for (int i=0;i<4;i++){ int c = tid+256*i; out[(size_t)row*ldo+c] = f2bf((v[i]-mean)*rstd*g[c]+bta[c]); }
}

// ---------------- time-embedding GEMM ----------------
__global__ __launch_bounds__(256) void tq_gemm2(const float* __restrict__ t, const float* __restrict__ tw,
                                                const float* __restrict__ tb, float* __restrict__ tq){
  const int tid = threadIdx.x;
  const int j = blockIdx.x*64 + (tid & 63);
  const int sl = tid >> 6;
  float acc[4] = {0.f,0.f,0.f,0.f};
  for (int k = sl*64; k < sl*64+64; ++k){
    float wv = tw[(size_t)k*3072 + j];
    #pragma unroll
    for (int b=0;b<4;b++) acc[b] = fmaf(t[b*256+k], wv, acc[b]);
  }
  __shared__ float red[4][4][64];
  #pragma unroll
  for (int b=0;b<4;b++) red[sl][b][tid&63] = acc[b];
  __syncthreads();
  if (sl == 0){
    #pragma unroll
    for (int b=0;b<4;b++)
      tq[b*3072 + j] = red[0][b][tid&63] + red[1][b][tid&63] + red[2][b][tid&63] + red[3][b][tid&63] + tb[j];
  }
}

// ---------------- gemm9: 128xTN, BK=32, 3-slot counted-vmcnt pipeline + 4x4 grouped raster ----
// EPI 0: bf16 = acc + bias + tqkv ; EPI 1: f32 = acc + bias + extra ; EPI 2: bf16 = gelu(acc+bias)
template<int EPI, int TN>
__global__ __launch_bounds__(256) void gemm9(
    const ushort* __restrict__ A, const ushort* __restrict__ Bt,
    const float* __restrict__ bias, const float* __restrict__ extra,
    ushort* __restrict__ outb, float* __restrict__ outf,
    int K, int lda, int ldb, int ldo, int lde, int nbx)
{
  constexpr int NJ = TN/32;
  __shared__ __align__(16) ushort Al[3][128*32];
  __shared__ __align__(16) ushort Bl[3][TN*32];
  const int nwg = gridDim.x, cpx = nwg >> 3;
  const int bid = blockIdx.x;
  const int swz = (bid & 7)*cpx + (bid >> 3);
  const int rowblk = swz / (nbx*4);
  const int lo2 = swz % (nbx*4);
  const int grp = lo2 >> 4;
  const int ir = (lo2 >> 2) & 3, ic = lo2 & 3;
  const int m0 = (rowblk*4 + ir)*128;
  const int n0 = (grp*4 + ic)*TN;
  const int tid = threadIdx.x, lane = tid & 63, wid = tid >> 6;
  const int wm = (wid&1)*64, wn = (wid>>1)*(TN/2);
  const int l15 = lane&15, l4 = lane>>4;
  f32x4 acc[4][NJ];
  #pragma unroll
  for (int i=0;i<4;i++)
    #pragma unroll
    for (int jx=0;jx<NJ;jx++){ acc[i][jx][0]=0.f; acc[i][jx][1]=0.f; acc[i][jx][2]=0.f; acc[i][jx][3]=0.f; }
  const ushort* a0p = A + (size_t)(m0 + (tid>>2))*lda + (tid&3)*8;
  const ushort* a1p = A + (size_t)(m0 + 64 + (tid>>2))*lda + (tid&3)*8;
  const ushort* b0p = Bt + (size_t)(n0 + (tid>>2))*ldb + (tid&3)*8;
  const ushort* b1p = nullptr;
  if constexpr (TN==128) b1p = Bt + (size_t)(n0 + 64 + (tid>>2))*ldb + (tid&3)*8;
  const int lsl = tid*8, lsh = (tid+256)*8;

  auto stage = [&](int s, int k1){
    gl2lds16(a0p + k1, &Al[s][lsl]);
    gl2lds16(a1p + k1, &Al[s][lsh]);
    gl2lds16(b0p + k1, &Bl[s][lsl]);
    if constexpr (TN==128) gl2lds16(b1p + k1, &Bl[s][lsh]);
  };

  const int nk = K >> 5;
  stage(0, 0);
  stage(1, 32);
  int s = 0;
  for (int it=0; it<nk; ++it){
    if constexpr (TN==128)
      asm volatile("s_waitcnt vmcnt(4) lgkmcnt(0)" ::: "memory");
    else
      asm volatile("s_waitcnt vmcnt(3) lgkmcnt(0)" ::: "memory");
    __builtin_amdgcn_sched_barrier(0);
    __builtin_amdgcn_s_barrier();
    if (it+2 < nk){
      int s2 = s + 2; if (s2 >= 3) s2 -= 3;
      stage(s2, (it+2) << 5);
    }
    ushort* Ac = Al[s];  ushort* Bc = Bl[s];
    short8 af[4], bfr[NJ];
    #pragma unroll
    for (int mi=0;mi<4;mi++) af[mi]  = *(const short8*)&Ac[(wm + mi*16 + l15)*32 + l4*8];
    #pragma unroll
    for (int nj=0;nj<NJ;nj++) bfr[nj] = *(const short8*)&Bc[(wn + nj*16 + l15)*32 + l4*8];
    #pragma unroll
    for (int mi=0;mi<4;mi++)
      #pragma unroll
      for (int nj=0;nj<NJ;nj++)
        acc[mi][nj] = __builtin_amdgcn_mfma_f32_16x16x32_bf16(af[mi], bfr[nj], acc[mi][nj], 0,0,0);
    if (++s >= 3) s = 0;
  }
  #pragma unroll
  for (int mi=0;mi<4;mi++)
    #pragma unroll
    for (int nj=0;nj<NJ;nj++)
      #pragma unroll
      for (int j=0;j<4;j++){
        int row = m0 + wm + mi*16 + l4*4 + j;
        int col = n0 + wn + nj*16 + l15;
        float v = acc[mi][nj][j] + bias[col];
        if constexpr (EPI==0){ v += extra[(size_t)(row>>10)*lde + col]; outb[(size_t)row*ldo+col] = f2bf(v); }
        else if constexpr (EPI==1){ v += extra[(size_t)row*lde + col]; outf[(size_t)row*ldo+col] = v; }
        else { outb[(size_t)row*ldo+col] = f2bf(gelu_exact(v)); }
      }
}

// ---------------- relskew8_v5: tiled int8 skew, COALESCED uint4 dump ----------------
__global__ __launch_bounds__(256) void relskew8_v5(
    const ushort* __restrict__ qkv, const ushort* __restrict__ Er,
    signed char* __restrict__ srelT)
{
  const int bid0 = blockIdx.x;
  const int swz = (bid0 & 7)*256 + (bid0 >> 3);
  const int bh = swz >> 5, b = bh >> 4, h = bh & 15;
  const int r0 = (swz & 31)*32;
  const int tid = threadIdx.x, w = tid >> 6, lane = tid & 63;
  const int l31 = lane & 31, hi = lane >> 5;

  __shared__ signed char T8[33*1044];
  signed char* srb = srelT + (size_t)bh*32*32*1024;

  if (tid < 33){
    int tgt = r0 - 1 + tid;
    int c = tgt + 1;
    if (tgt >= 0 && c <= 1023) T8[tid*1044 + c] = 0;
  }

  const ushort* Qp = qkv + (size_t)b*1024*3200 + h*64;
  const int r = r0 + l31;
  short8 qf0 = *(const short8*)(Qp + (size_t)r*3200 +      hi*8);
  short8 qf1 = *(const short8*)(Qp + (size_t)r*3200 + 16 + hi*8);
  short8 qf2 = *(const short8*)(Qp + (size_t)r*3200 + 32 + hi*8);
  short8 qf3 = *(const short8*)(Qp + (size_t)r*3200 + 48 + hi*8);

  const float ESC = 92.332481f;
  for (int t=0; t<8; ++t){
    const int e0 = w*256 + t*32;
    const ushort* ep = Er + (size_t)(e0 + l31)*64 + hi*8;
    short8 ea0 = *(const short8*)(ep);
    short8 ea1 = *(const short8*)(ep + 16);
    short8 ea2 = *(const short8*)(ep + 32);
    short8 ea3 = *(const short8*)(ep + 48);
    f32x16 acc = {};
    acc = mfma32(ea0, qf0, acc);
    acc = mfma32(ea1, qf1, acc);
    acc = mfma32(ea2, qf2, acc);
    acc = mfma32(ea3, qf3, acc);
    #pragma unroll
    for (int q=0;q<4;q++)
      #pragma unroll
      for (int j=0;j<4;j++){
        int e = e0 + 8*q + 4*hi + j;
        signed char v = (signed char)(int)q8(acc[4*q+j]*ESC);
        bool below = (e + r) >= 1023;
        int i = below ? (l31 + 1) : l31;
        int c = e + r + (below ? -1023 : 1);
        T8[i*1044 + c] = v;
      }
  }
  __syncthreads();

  const int rt = r0 >> 5;
  const bool lastfull = (r0 == 992);
  signed char* base = srb + (size_t)rt*32768;
  #pragma unroll
  for (int p=0; p<8; ++p){
    int off = p*4096 + tid*16;
    int ct = off >> 10;
    int wi = off & 1023;
    int row = wi >> 5;
    int sh = wi & 31;
    int i = row + 1;
    int g0 = sh ? 4 : 0;
    const signed char* src = T8 + i*1044 + ct*32;
    uint4 u;
    u.x = *(const uint*)(src + g0);
    u.y = *(const uint*)(src + g0 + 8);
    u.z = *(const uint*)(src + g0 + 16);
    u.w = *(const uint*)(src + g0 + 24);
    if (row < 31 || lastfull){
      *(uint4*)(base + off) = u;
    } else if (ct <= rt){
      *(uint4*)(base + off) = u;
    } else if (ct == rt+1 && sh == 0){
      base[off] = ((const signed char*)&u)[0];
    }
  }
  if (r0 > 0 && tid < 64){
    int ct = tid >> 1, sh = (tid & 1)*16;
    int g0 = sh ? 4 : 0;
    const signed char* src = T8 + ct*32;
    signed char* tbase = srb + ((size_t)(rt-1)*32 + ct)*1024 + 31*32 + sh;
    if (ct > rt || (ct == rt && sh == 16)){
      uint4 u;
      u.x = *(const uint*)(src + g0);
      u.y = *(const uint*)(src + g0 + 8);
      u.z = *(const uint*)(src + g0 + 16);
      u.w = *(const uint*)(src + g0 + 24);
      *(uint4*)tbase = u;
    } else if (ct == rt && sh == 0){
      #pragma unroll
      for (int s2=1; s2<16; ++s2){
        int col = (s2>>2)*8 + (s2&3);
        tbase[s2] = src[col];
      }
    }
  }
}

// ---------------- attn11: 32x32 flash, ONE uint4 tiled bias load/step ----------------
__global__ __launch_bounds__(256) void attn11(
    const ushort* __restrict__ qkv, const signed char* __restrict__ srelT,
    const ushort* __restrict__ Vt, ushort* __restrict__ out)
{
  const int bid0 = blockIdx.x;
  const int swz = (bid0 & 7)*64 + (bid0 >> 3);
  const int bh = swz >> 3, b = bh >> 4, h = bh & 15;
  const int rblk = (swz & 7)*128;
  const int tid = threadIdx.x, w = tid >> 6, lane = tid & 63;
  const int l31 = lane & 31, hi = lane >> 5;
  const int r = rblk + w*32 + l31;
  const ushort* Qp = qkv + (size_t)b*1024*3200 + h*64;
  const ushort* Kp = Qp + 1024;
  const ushort* Vp = Vt + (size_t)bh*64*1152;
  const signed char* BpT = srelT + ((size_t)bh*32 + (r>>5))*32*1024 + (r&31)*32 + hi*16;

  short8 qf0 = *(const short8*)(Qp + (size_t)r*3200 +      hi*8);
  short8 qf1 = *(const short8*)(Qp + (size_t)r*3200 + 16 + hi*8);
  short8 qf2 = *(const short8*)(Qp + (size_t)r*3200 + 32 + hi*8);
  short8 qf3 = *(const short8*)(Qp + (size_t)r*3200 + 48 + hi*8);

  f32x16 O0 = {}, O1 = {};
  float lsum = 0.f;

  short8 kA0 = *(const short8*)(Kp + (size_t)l31*3200 +      hi*8);
  short8 kA1 = *(const short8*)(Kp + (size_t)l31*3200 + 16 + hi*8);
  short8 kA2 = *(const short8*)(Kp + (size_t)l31*3200 + 32 + hi*8);
  short8 kA3 = *(const short8*)(Kp + (size_t)l31*3200 + 48 + hi*8);
  short8 kB0, kB1, kB2, kB3;

  auto step = [&](short8& ka0, short8& ka1, short8& ka2, short8& ka3,
                  short8& kn0, short8& kn1, short8& kn2, short8& kn3, int t){
    const int c0 = t*32;
    if (t < 31){
      const ushort* kp = Kp + (size_t)(c0 + 32 + l31)*3200 + hi*8;
      kn0 = *(const short8*)(kp);
      kn1 = *(const short8*)(kp + 16);
      kn2 = *(const short8*)(kp + 32);
      kn3 = *(const short8*)(kp + 48);
    }
    uint4 bw = *(const uint4*)(BpT + (size_t)t*1024);
    const signed char* bb = (const signed char*)&bw;
    short8 v00 = *(const short8*)(Vp + (size_t)l31*1152      + c0 +      hi*8);
    short8 v01 = *(const short8*)(Vp + (size_t)l31*1152      + c0 + 16 + hi*8);
    short8 v10 = *(const short8*)(Vp + (size_t)(32+l31)*1152 + c0 +      hi*8);
    short8 v11 = *(const short8*)(Vp + (size_t)(32+l31)*1152 + c0 + 16 + hi*8);
    f32x16 S = {};
    __builtin_amdgcn_s_setprio(1);
    S = mfma32(ka0, qf0, S);
    S = mfma32(ka1, qf1, S);
    S = mfma32(ka2, qf2, S);
    S = mfma32(ka3, qf3, S);
    __builtin_amdgcn_s_setprio(0);
    float p[16];
    float s0=0.f, s1=0.f, s2=0.f, s3=0.f;
    #pragma unroll
    for (int i=0;i<16;i++){
      float pv = __builtin_amdgcn_exp2f(fmaf(S[i], 0.18033688f, (float)bb[i]*0.015625f));
      p[i] = pv;
      if ((i&3)==0) s0 += pv; else if ((i&3)==1) s1 += pv;
      else if ((i&3)==2) s2 += pv; else s3 += pv;
    }
    lsum += (s0+s1)+(s2+s3);
    uint W00=cvtpk(p[0],p[1]),   W01=cvtpk(p[2],p[3]);
    uint W10=cvtpk(p[4],p[5]),   W11=cvtpk(p[6],p[7]);
    uint W20=cvtpk(p[8],p[9]),   W21=cvtpk(p[10],p[11]);
    uint W30=cvtpk(p[12],p[13]), W31=cvtpk(p[14],p[15]);
    uint x00 = (uint)__shfl_xor((int)(hi? W00 : W10), 32, 64);
    uint x01 = (uint)__shfl_xor((int)(hi? W01 : W11), 32, 64);
    uint x10 = (uint)__shfl_xor((int)(hi? W20 : W30), 32, 64);
    uint x11 = (uint)__shfl_xor((int)(hi? W21 : W31), 32, 64);
    union { uint u[4]; short8 v; } pf0, pf1;
    pf0.u[0] = hi ? x00 : W00;  pf0.u[1] = hi ? x01 : W01;
    pf0.u[2] = hi ? W10 : x00;  pf0.u[3] = hi ? W11 : x01;
    pf1.u[0] = hi ? x10 : W20;  pf1.u[1] = hi ? x11 : W21;
    pf1.u[2] = hi ? W30 : x10;  pf1.u[3] = hi ? W31 : x11;
    __builtin_amdgcn_s_setprio(1);
    O0 = mfma32(v00, pf0.v, O0);
    O0 = mfma32(v01, pf1.v, O0);
    O1 = mfma32(v10, pf0.v, O1);
    O1 = mfma32(v11, pf1.v, O1);
    __builtin_amdgcn_s_setprio(0);
  };
  for (int t=0;t<32;t+=2){
    step(kA0,kA1,kA2,kA3, kB0,kB1,kB2,kB3, t);
    step(kB0,kB1,kB2,kB3, kA0,kA1,kA2,kA3, t+1);
  }
  float inv = 1.f/(lsum + __shfl_xor(lsum, 32, 64));
  ushort* op = out + ((size_t)(b*1024 + r))*1152 + h*64;
  #pragma unroll
  for (int rq=0;rq<4;rq++)
    #pragma unroll
    for (int s=0;s<2;s++){
      int reg = rq*4 + s*2;
      uint w0 = cvtpk(O0[reg]*inv, O0[reg+1]*inv);
      uint w1 = cvtpk(O1[reg]*inv, O1[reg+1]*inv);
      int d = rq*8 + hi*4 + s*2;
      *(uint*)(op + d) = w0;
      *(uint*)(op + 32 + d) = w1;
    }
}

extern "C" void kernel_launch(void* const* d_in, const int* in_sizes, int n_in,
                              void* d_out, int out_size, void* d_ws, size_t ws_size,
                              hipStream_t stream)
{
  const float* x    = (const float*)d_in[0];
  const float* t    = (const float*)d_in[1];
  const float* ln1g = (const float*)d_in[2];
  const float* ln1b = (const float*)d_in[3];
  const float* qkvw = (const float*)d_in[4];
  const float* qkvb = (const float*)d_in[5];
  const float* timew= (const float*)d_in[6];
  const float* timeb= (const float*)d_in[7];
  const float* outw = (const float*)d_in[8];
  const float* outbv= (const float*)d_in[9];
  const float* Er   = (const float*)d_in[10];
  const float* ln2g = (const float*)d_in[11];
  const float* ln2b = (const float*)d_in[12];
  const float* ff1w = (const float*)d_in[13];
  const float* ff1b = (const float*)d_in[14];
  const float* ff2w = (const float*)d_in[15];
  const float* ff2b = (const float*)d_in[16];
  float* o = (float*)d_out;

  char* ws = (char*)d_ws;
  ushort* qkvw_t = (ushort*)(ws);              // [3072][1152]
  ushort* outw_t = (ushort*)(ws + 7077888);    // [1024][1152]
  ushort* ff1w_t = (ushort*)(ws + 9437184);    // [4096][1152]
  ushort* ff2w_t = (ushort*)(ws + 18874368);   // [1024][4224]
  ushort* er_b   = (ushort*)(ws + 27525120);   // [1024][64]
  float*  tq     = (float*) (ws + 27656192);   // [4][3072]
  ushort* bufA   = (ushort*)(ws + 27705344);   // [4096][1152]
  ushort* vt     = (ushort*)(ws + 37142528);   // [4096][1152]
  ushort* bufB   = (ushort*)(ws + 46579712);   // [4096][4224] (qkv at stride 3200 / ff1o at 4224)
  signed char* srelT = (signed char*)(ws + 81182720);  // [64][32][32][1024] tiled int8 (67.1 MB)

  wt_cvt<<<dim3(48,16),256,0,stream>>>(qkvw, qkvw_t, 1024, 3072, 1152);
  wt_cvt<<<dim3(16,16),256,0,stream>>>(outw, outw_t, 1024, 1024, 1152);
  wt_cvt<<<dim3(64,16),256,0,stream>>>(ff1w, ff1w_t, 1024, 4096, 1152);
  wt_cvt<<<dim3(16,64),256,0,stream>>>(ff2w, ff2w_t, 4096, 1024, 4224);
  cvt_f2b<<<256,256,0,stream>>>(Er, er_b, 65536);

  ln_rows<<<4096,256,0,stream>>>(x, ln1g, ln1b, bufA, 1152);
  tq_gemm2<<<48,256,0,stream>>>(t, timew, timeb, tq);
  gemm9<0,128><<<768,256,0,stream>>>(bufA, qkvw_t, qkvb, tq, bufB, nullptr,
                                     1024, 1152, 1152, 3200, 3072, 24);
  vt_k<<<dim3(16,64),256,0,stream>>>(bufB, vt);
  relskew8_v5<<<2048,256,0,stream>>>(bufB, er_b, srelT);
  attn11<<<512,256,0,stream>>>(bufB, srelT, vt, bufA);
  gemm9<1,64><<<512,256,0,stream>>>(bufA, outw_t, outbv, x, nullptr, o,
                                    1024, 1152, 1152, 1024, 1024, 16);
  ln_rows<<<4096,256,0,stream>>>(o, ln2g, ln2b, bufA, 1152);
  gemm9<2,128><<<1024,256,0,stream>>>(bufA, ff1w_t, ff1b, nullptr, bufB, nullptr,
                                      1024, 1152, 1152, 4224, 0, 32);
  gemm9<1,64><<<512,256,0,stream>>>(bufB, ff2w_t, ff2b, o, nullptr, o,
                                    4096, 4224, 4224, 1024, 1024, 16);
}

// Round 22
// 338.229 us; speedup vs baseline: 1.0207x; 1.0123x over previous
//
#include <hip/hip_runtime.h>
#include <hip/hip_bf16.h>

typedef __attribute__((ext_vector_type(8))) short short8;
typedef __attribute__((ext_vector_type(4))) float f32x4;
typedef __attribute__((ext_vector_type(16))) float f32x16;

#define DEV __device__ __forceinline__

DEV float bf2f(ushort u){ union { float f; unsigned int i; } x; x.i = ((unsigned int)u)<<16; return x.f; }
DEV ushort f2bf(float f){ union { float fl; unsigned int i; } x; x.fl = f; unsigned int r = x.i + 0x7fffu + ((x.i>>16)&1u); return (ushort)(r>>16); }

DEV void gl2lds16(const ushort* g, ushort* l){
  __builtin_amdgcn_global_load_lds((const __attribute__((address_space(1))) void*)g,
                                   (__attribute__((address_space(3))) void*)l, 16, 0, 0);
}
DEV f32x16 mfma32(short8 a, short8 b, f32x16 c){
  return __builtin_amdgcn_mfma_f32_32x32x16_bf16(a, b, c, 0, 0, 0);
}
DEV uint cvtpk(float lo, float hi){
  uint r; asm("v_cvt_pk_bf16_f32 %0, %1, %2" : "=v"(r) : "v"(lo), "v"(hi));
  return r;
}
DEV uint q8(float v){
  float c = fminf(fmaxf(v, -127.f), 127.f);
  return ((uint)(int)rintf(c)) & 255u;
}
// A&S 7.1.26 erf, |err| <= 1.5e-7
DEV float gelu_exact(float xx){
  float z = fabsf(xx) * 0.70710678118f;
  float tt = __builtin_amdgcn_rcpf(fmaf(0.3275911f, z, 1.f));
  float poly = fmaf(fmaf(fmaf(fmaf(1.061405429f, tt, -1.453152027f), tt, 1.421413741f),
                         tt, -0.284496736f), tt, 0.254829592f) * tt;
  float e = __builtin_amdgcn_exp2f(-z*z*1.4426950408f);
  float er = fmaf(-poly, e, 1.f);
  er = (xx < 0.f) ? -er : er;
  return 0.5f*xx*(1.f+er);
}

// ---------------- fp32 -> bf16 convert (Er only) ----------------
__global__ void cvt_f2b(const float* __restrict__ in, ushort* __restrict__ out, int n){
  int i = blockIdx.x*blockDim.x + threadIdx.x;
  int stride = gridDim.x*blockDim.x;
  for (; i < n; i += stride) out[i] = f2bf(in[i]);
}

// ---------------- fp32 [K][N] -> bf16 [N][K+pad] tiled transpose ----------------
__global__ __launch_bounds__(256) void wt_cvt(const float* __restrict__ in, ushort* __restrict__ out,
                                              int K, int N, int ldk){
  const int n0 = blockIdx.x*64, k0 = blockIdx.y*64;
  __shared__ float T[64][65];
  const int tid = threadIdx.x;
  const int r = tid>>4, c = (tid&15)*4;
  #pragma unroll
  for (int p=0;p<4;p++){
    float4 v = *(const float4*)&in[(size_t)(k0 + p*16 + r)*N + n0 + c];
    T[p*16+r][c+0]=v.x; T[p*16+r][c+1]=v.y; T[p*16+r][c+2]=v.z; T[p*16+r][c+3]=v.w;
  }
  __syncthreads();
  #pragma unroll
  for (int p=0;p<4;p++){
    int n = p*16 + r;
    ushort u0 = f2bf(T[c+0][n]), u1 = f2bf(T[c+1][n]), u2 = f2bf(T[c+2][n]), u3 = f2bf(T[c+3][n]);
    ushort4 u = make_ushort4(u0,u1,u2,u3);
    *(ushort4*)&out[(size_t)(n0+n)*ldk + k0 + c] = u;
  }
}

// ---------------- V transpose ----------------
__global__ __launch_bounds__(256) void vt_k(const ushort* __restrict__ qkv, ushort* __restrict__ vt){
  const int bh = blockIdx.y; const int b = bh>>4, h = bh&15;
  const int n0 = blockIdx.x*64;
  __shared__ ushort T[64][66];
  const int tid = threadIdx.x;
  const int r = tid>>3, c8 = (tid&7)*8;
  #pragma unroll
  for (int p=0;p<2;p++){
    int row = p*32 + r;
    short8 v = *(const short8*)&qkv[(size_t)(b*1024 + n0 + row)*3200 + 2048 + h*64 + c8];
    #pragma unroll
    for (int i=0;i<8;i++) T[row][c8+i] = ((ushort*)&v)[i];
  }
  __syncthreads();
  #pragma unroll
  for (int p=0;p<2;p++){
    int d = p*32 + r;
    union { ushort u[8]; short8 v; } o;
    #pragma unroll
    for (int i=0;i<8;i++) o.u[i] = T[c8+i][d];
    *(short8*)&vt[(size_t)(bh*64 + d)*1152 + n0 + c8] = o.v;
  }
}

// ---------------- LayerNorm over C=1024 ----------------
__global__ __launch_bounds__(256) void ln_rows(const float* __restrict__ in,
                                               const float* __restrict__ g,
                                               const float* __restrict__ bta,
                                               ushort* __restrict__ out, int ldo){
  int row = blockIdx.x; int tid = threadIdx.x;
  const float* x = in + (size_t)row*1024;
  float v[4]; float s = 0.f;
  #pragma unroll
  for (int i=0;i<4;i++){ v[i] = x[tid + 256*i]; s += v[i]; }
  __shared__ float rbuf[256];
  rbuf[tid] = s; __syncthreads();
  for (int off=128; off>0; off>>=1){ if (tid<off) rbuf[tid]+=rbuf[tid+off]; __syncthreads(); }
  float mean = rbuf[0] * (1.f/1024.f);
  __syncthreads();
  float s2 = 0.f;
  #pragma unroll
  for (int i=0;i<4;i++){ float d=v[i]-mean; s2 += d*d; }
  rbuf[tid] = s2; __syncthreads();
  for (int off=128; off>0; off>>=1){ if (tid<off) rbuf[tid]+=rbuf[tid+off]; __syncthreads(); }
  float var = rbuf[0] * (1.f/1024.f);
  float rstd = rsqrtf(var + 1e-5f);
  #pragma unroll
  for (int i=0;i<4;i++){ int c = tid+256*i; out[(size_t)row*ldo+c] = f2bf((v[i]-mean)*rstd*g[c]+bta[c]); }
}

// ---------------- time-embedding GEMM ----------------
__global__ __launch_bounds__(256) void tq_gemm2(const float* __restrict__ t, const float* __restrict__ tw,
                                                const float* __restrict__ tb, float* __restrict__ tq){
  const int tid = threadIdx.x;
  const int j = blockIdx.x*64 + (tid & 63);
  const int sl = tid >> 6;
  float acc[4] = {0.f,0.f,0.f,0.f};
  for (int k = sl*64; k < sl*64+64; ++k){
    float wv = tw[(size_t)k*3072 + j];
    #pragma unroll
    for (int b=0;b<4;b++) acc[b] = fmaf(t[b*256+k], wv, acc[b]);
  }
  __shared__ float red[4][4][64];
  #pragma unroll
  for (int b=0;b<4;b++) red[sl][b][tid&63] = acc[b];
  __syncthreads();
  if (sl == 0){
    #pragma unroll
    for (int b=0;b<4;b++)
      tq[b*3072 + j] = red[0][b][tid&63] + red[1][b][tid&63] + red[2][b][tid&63] + red[3][b][tid&63] + tb[j];
  }
}

// ---------------- gemm9: 128xTN, BK=32, 3-slot counted-vmcnt pipeline + 4x4 grouped raster ----
template<int EPI, int TN>
__global__ __launch_bounds__(256) void gemm9(
    const ushort* __restrict__ A, const ushort* __restrict__ Bt,
    const float* __restrict__ bias, const float* __restrict__ extra,
    ushort* __restrict__ outb, float* __restrict__ outf,
    int K, int lda, int ldb, int ldo, int lde, int nbx)
{
  constexpr int NJ = TN/32;
  __shared__ __align__(16) ushort Al[3][128*32];
  __shared__ __align__(16) ushort Bl[3][TN*32];
  const int nwg = gridDim.x, cpx = nwg >> 3;
  const int bid = blockIdx.x;
  const int swz = (bid & 7)*cpx + (bid >> 3);
  const int rowblk = swz / (nbx*4);
  const int lo2 = swz % (nbx*4);
  const int grp = lo2 >> 4;
  const int ir = (lo2 >> 2) & 3, ic = lo2 & 3;
  const int m0 = (rowblk*4 + ir)*128;
  const int n0 = (grp*4 + ic)*TN;
  const int tid = threadIdx.x, lane = tid & 63, wid = tid >> 6;
  const int wm = (wid&1)*64, wn = (wid>>1)*(TN/2);
  const int l15 = lane&15, l4 = lane>>4;
  f32x4 acc[4][NJ];
  #pragma unroll
  for (int i=0;i<4;i++)
    #pragma unroll
    for (int jx=0;jx<NJ;jx++){ acc[i][jx][0]=0.f; acc[i][jx][1]=0.f; acc[i][jx][2]=0.f; acc[i][jx][3]=0.f; }
  const ushort* a0p = A + (size_t)(m0 + (tid>>2))*lda + (tid&3)*8;
  const ushort* a1p = A + (size_t)(m0 + 64 + (tid>>2))*lda + (tid&3)*8;
  const ushort* b0p = Bt + (size_t)(n0 + (tid>>2))*ldb + (tid&3)*8;
  const ushort* b1p = nullptr;
  if constexpr (TN==128) b1p = Bt + (size_t)(n0 + 64 + (tid>>2))*ldb + (tid&3)*8;
  const int lsl = tid*8, lsh = (tid+256)*8;

  auto stage = [&](int s, int k1){
    gl2lds16(a0p + k1, &Al[s][lsl]);
    gl2lds16(a1p + k1, &Al[s][lsh]);
    gl2lds16(b0p + k1, &Bl[s][lsl]);
    if constexpr (TN==128) gl2lds16(b1p + k1, &Bl[s][lsh]);
  };

  const int nk = K >> 5;
  stage(0, 0);
  stage(1, 32);
  int s = 0;
  for (int it=0; it<nk; ++it){
    if constexpr (TN==128)
      asm volatile("s_waitcnt vmcnt(4) lgkmcnt(0)" ::: "memory");
    else
      asm volatile("s_waitcnt vmcnt(3) lgkmcnt(0)" ::: "memory");
    __builtin_amdgcn_sched_barrier(0);
    __builtin_amdgcn_s_barrier();
    if (it+2 < nk){
      int s2 = s + 2; if (s2 >= 3) s2 -= 3;
      stage(s2, (it+2) << 5);
    }
    ushort* Ac = Al[s];  ushort* Bc = Bl[s];
    short8 af[4], bfr[NJ];
    #pragma unroll
    for (int mi=0;mi<4;mi++) af[mi]  = *(const short8*)&Ac[(wm + mi*16 + l15)*32 + l4*8];
    #pragma unroll
    for (int nj=0;nj<NJ;nj++) bfr[nj] = *(const short8*)&Bc[(wn + nj*16 + l15)*32 + l4*8];
    #pragma unroll
    for (int mi=0;mi<4;mi++)
      #pragma unroll
      for (int nj=0;nj<NJ;nj++)
        acc[mi][nj] = __builtin_amdgcn_mfma_f32_16x16x32_bf16(af[mi], bfr[nj], acc[mi][nj], 0,0,0);
    if (++s >= 3) s = 0;
  }
  #pragma unroll
  for (int mi=0;mi<4;mi++)
    #pragma unroll
    for (int nj=0;nj<NJ;nj++)
      #pragma unroll
      for (int j=0;j<4;j++){
        int row = m0 + wm + mi*16 + l4*4 + j;
        int col = n0 + wn + nj*16 + l15;
        float v = acc[mi][nj][j] + bias[col];
        if constexpr (EPI==0){ v += extra[(size_t)(row>>10)*lde + col]; outb[(size_t)row*ldo+col] = f2bf(v); }
        else if constexpr (EPI==1){ v += extra[(size_t)row*lde + col]; outf[(size_t)row*ldo+col] = v; }
        else { outb[(size_t)row*ldo+col] = f2bf(gelu_exact(v)); }
      }
}

// ---------------- gemm10: 256x256 tile, BK=32, 512 threads (8 waves 2Mx4N), 3-slot pipeline ----
// Same proven sync structure as gemm9 (counted vmcnt + raw barrier), scaled to 256^2:
// 32 MFMA per barrier-pair (vs 16), 4 staged loads/iter. LDS 96KB -> 1 WG/CU (full chip at 256 WGs).
template<int EPI>
__global__ __launch_bounds__(512) void gemm10(
    const ushort* __restrict__ A, const ushort* __restrict__ Bt,
    const float* __restrict__ bias, const float* __restrict__ extra,
    ushort* __restrict__ outb, float* __restrict__ outf,
    int K, int lda, int ldb, int ldo, int lde, int nbx)
{
  __shared__ __align__(16) ushort Al[3][256*32];
  __shared__ __align__(16) ushort Bl[3][256*32];
  const int nwg = gridDim.x, cpx = nwg >> 3;
  const int bid = blockIdx.x;
  const int swz = (bid & 7)*cpx + (bid >> 3);
  const int rowblk = swz / (nbx*4);
  const int lo2 = swz % (nbx*4);
  const int grp = lo2 >> 4;
  const int ir = (lo2 >> 2) & 3, ic = lo2 & 3;
  const int m0 = (rowblk*4 + ir)*256;
  const int n0 = (grp*4 + ic)*256;
  const int tid = threadIdx.x, lane = tid & 63, wid = tid >> 6;
  const int wm = (wid&1)*128, wn = (wid>>1)*64;
  const int l15 = lane&15, l4 = lane>>4;
  f32x4 acc[8][4];
  #pragma unroll
  for (int i=0;i<8;i++)
    #pragma unroll
    for (int jx=0;jx<4;jx++){ acc[i][jx][0]=0.f; acc[i][jx][1]=0.f; acc[i][jx][2]=0.f; acc[i][jx][3]=0.f; }
  // staging: A-tile 256x32 = 1024 chunks of 16B; thread covers chunks tid and tid+512
  const ushort* a0p = A + (size_t)(m0 + (tid>>2))*lda + (tid&3)*8;
  const ushort* a1p = A + (size_t)(m0 + 128 + (tid>>2))*lda + (tid&3)*8;
  const ushort* b0p = Bt + (size_t)(n0 + (tid>>2))*ldb + (tid&3)*8;
  const ushort* b1p = Bt + (size_t)(n0 + 128 + (tid>>2))*ldb + (tid&3)*8;
  const int lsl = tid*8, lsh = (tid+512)*8;

  auto stage = [&](int s, int k1){
    gl2lds16(a0p + k1, &Al[s][lsl]);
    gl2lds16(a1p + k1, &Al[s][lsh]);
    gl2lds16(b0p + k1, &Bl[s][lsl]);
    gl2lds16(b1p + k1, &Bl[s][lsh]);
  };

  const int nk = K >> 5;
  stage(0, 0);
  stage(1, 32);
  int s = 0;
  for (int it=0; it<nk; ++it){
    asm volatile("s_waitcnt vmcnt(4) lgkmcnt(0)" ::: "memory");
    __builtin_amdgcn_sched_barrier(0);
    __builtin_amdgcn_s_barrier();
    if (it+2 < nk){
      int s2 = s + 2; if (s2 >= 3) s2 -= 3;
      stage(s2, (it+2) << 5);
    }
    ushort* Ac = Al[s];  ushort* Bc = Bl[s];
    short8 af[8], bfr[4];
    #pragma unroll
    for (int mi=0;mi<8;mi++) af[mi]  = *(const short8*)&Ac[(wm + mi*16 + l15)*32 + l4*8];
    #pragma unroll
    for (int nj=0;nj<4;nj++) bfr[nj] = *(const short8*)&Bc[(wn + nj*16 + l15)*32 + l4*8];
    __builtin_amdgcn_s_setprio(1);
    #pragma unroll
    for (int mi=0;mi<8;mi++)
      #pragma unroll
      for (int nj=0;nj<4;nj++)
        acc[mi][nj] = __builtin_amdgcn_mfma_f32_16x16x32_bf16(af[mi], bfr[nj], acc[mi][nj], 0,0,0);
    __builtin_amdgcn_s_setprio(0);
    if (++s >= 3) s = 0;
  }
  #pragma unroll
  for (int mi=0;mi<8;mi++)
    #pragma unroll
    for (int nj=0;nj<4;nj++)
      #pragma unroll
      for (int j=0;j<4;j++){
        int row = m0 + wm + mi*16 + l4*4 + j;
        int col = n0 + wn + nj*16 + l15;
        float v = acc[mi][nj][j] + bias[col];
        if constexpr (EPI==0){ v += extra[(size_t)(row>>10)*lde + col]; outb[(size_t)row*ldo+col] = f2bf(v); }
        else if constexpr (EPI==1){ v += extra[(size_t)row*lde + col]; outf[(size_t)row*ldo+col] = v; }
        else { outb[(size_t)row*ldo+col] = f2bf(gelu_exact(v)); }
      }
}

// ---------------- relskew8_v5: tiled int8 skew, COALESCED uint4 dump ----------------
__global__ __launch_bounds__(256) void relskew8_v5(
    const ushort* __restrict__ qkv, const ushort* __restrict__ Er,
    signed char* __restrict__ srelT)
{
  const int bid0 = blockIdx.x;
  const int swz = (bid0 & 7)*256 + (bid0 >> 3);
  const int bh = swz >> 5, b = bh >> 4, h = bh & 15;
  const int r0 = (swz & 31)*32;
  const int tid = threadIdx.x, w = tid >> 6, lane = tid & 63;
  const int l31 = lane & 31, hi = lane >> 5;

  __shared__ signed char T8[33*1044];
  signed char* srb = srelT + (size_t)bh*32*32*1024;

  if (tid < 33){
    int tgt = r0 - 1 + tid;
    int c = tgt + 1;
    if (tgt >= 0 && c <= 1023) T8[tid*1044 + c] = 0;
  }

  const ushort* Qp = qkv + (size_t)b*1024*3200 + h*64;
  const int r = r0 + l31;
  short8 qf0 = *(const short8*)(Qp + (size_t)r*3200 +      hi*8);
  short8 qf1 = *(const short8*)(Qp + (size_t)r*3200 + 16 + hi*8);
  short8 qf2 = *(const short8*)(Qp + (size_t)r*3200 + 32 + hi*8);
  short8 qf3 = *(const short8*)(Qp + (size_t)r*3200 + 48 + hi*8);

  const float ESC = 92.332481f;
  for (int t=0; t<8; ++t){
    const int e0 = w*256 + t*32;
    const ushort* ep = Er + (size_t)(e0 + l31)*64 + hi*8;
    short8 ea0 = *(const short8*)(ep);
    short8 ea1 = *(const short8*)(ep + 16);
    short8 ea2 = *(const short8*)(ep + 32);
    short8 ea3 = *(const short8*)(ep + 48);
    f32x16 acc = {};
    acc = mfma32(ea0, qf0, acc);
    acc = mfma32(ea1, qf1, acc);
    acc = mfma32(ea2, qf2, acc);
    acc = mfma32(ea3, qf3, acc);
    #pragma unroll
    for (int q=0;q<4;q++)
      #pragma unroll
      for (int j=0;j<4;j++){
        int e = e0 + 8*q + 4*hi + j;
        signed char v = (signed char)(int)q8(acc[4*q+j]*ESC);
        bool below = (e + r) >= 1023;
        int i = below ? (l31 + 1) : l31;
        int c = e + r + (below ? -1023 : 1);
        T8[i*1044 + c] = v;
      }
  }
  __syncthreads();

  const int rt = r0 >> 5;
  const bool lastfull = (r0 == 992);
  signed char* base = srb + (size_t)rt*32768;
  #pragma unroll
  for (int p=0; p<8; ++p){
    int off = p*4096 + tid*16;
    int ct = off >> 10;
    int wi = off & 1023;
    int row = wi >> 5;
    int sh = wi & 31;
    int i = row + 1;
    int g0 = sh ? 4 : 0;
    const signed char* src = T8 + i*1044 + ct*32;
    uint4 u;
    u.x = *(const uint*)(src + g0);
    u.y = *(const uint*)(src + g0 + 8);
    u.z = *(const uint*)(src + g0 + 16);
    u.w = *(const uint*)(src + g0 + 24);
    if (row < 31 || lastfull){
      *(uint4*)(base + off) = u;
    } else if (ct <= rt){
      *(uint4*)(base + off) = u;
    } else if (ct == rt+1 && sh == 0){
      base[off] = ((const signed char*)&u)[0];
    }
  }
  if (r0 > 0 && tid < 64){
    int ct = tid >> 1, sh = (tid & 1)*16;
    int g0 = sh ? 4 : 0;
    const signed char* src = T8 + ct*32;
    signed char* tbase = srb + ((size_t)(rt-1)*32 + ct)*1024 + 31*32 + sh;
    if (ct > rt || (ct == rt && sh == 16)){
      uint4 u;
      u.x = *(const uint*)(src + g0);
      u.y = *(const uint*)(src + g0 + 8);
      u.z = *(const uint*)(src + g0 + 16);
      u.w = *(const uint*)(src + g0 + 24);
      *(uint4*)tbase = u;
    } else if (ct == rt && sh == 0){
      #pragma unroll
      for (int s2=1; s2<16; ++s2){
        int col = (s2>>2)*8 + (s2&3);
        tbase[s2] = src[col];
      }
    }
  }
}

// ---------------- attn11: 32x32 flash, ONE uint4 tiled bias load/step ----------------
__global__ __launch_bounds__(256) void attn11(
    const ushort* __restrict__ qkv, const signed char* __restrict__ srelT,
    const ushort* __restrict__ Vt, ushort* __restrict__ out)
{
  const int bid0 = blockIdx.x;
  const int swz = (bid0 & 7)*64 + (bid0 >> 3);
  const int bh = swz >> 3, b = bh >> 4, h = bh & 15;
  const int rblk = (swz & 7)*128;
  const int tid = threadIdx.x, w = tid >> 6, lane = tid & 63;
  const int l31 = lane & 31, hi = lane >> 5;
  const int r = rblk + w*32 + l31;
  const ushort* Qp = qkv + (size_t)b*1024*3200 + h*64;
  const ushort* Kp = Qp + 1024;
  const ushort* Vp = Vt + (size_t)bh*64*1152;
  const signed char* BpT = srelT + ((size_t)bh*32 + (r>>5))*32*1024 + (r&31)*32 + hi*16;

  short8 qf0 = *(const short8*)(Qp + (size_t)r*3200 +      hi*8);
  short8 qf1 = *(const short8*)(Qp + (size_t)r*3200 + 16 + hi*8);
  short8 qf2 = *(const short8*)(Qp + (size_t)r*3200 + 32 + hi*8);
  short8 qf3 = *(const short8*)(Qp + (size_t)r*3200 + 48 + hi*8);

  f32x16 O0 = {}, O1 = {};
  float lsum = 0.f;

  short8 kA0 = *(const short8*)(Kp + (size_t)l31*3200 +      hi*8);
  short8 kA1 = *(const short8*)(Kp + (size_t)l31*3200 + 16 + hi*8);
  short8 kA2 = *(const short8*)(Kp + (size_t)l31*3200 + 32 + hi*8);
  short8 kA3 = *(const short8*)(Kp + (size_t)l31*3200 + 48 + hi*8);
  short8 kB0, kB1, kB2, kB3;

  auto step = [&](short8& ka0, short8& ka1, short8& ka2, short8& ka3,
                  short8& kn0, short8& kn1, short8& kn2, short8& kn3, int t){
    const int c0 = t*32;
    if (t < 31){
      const ushort* kp = Kp + (size_t)(c0 + 32 + l31)*3200 + hi*8;
      kn0 = *(const short8*)(kp);
      kn1 = *(const short8*)(kp + 16);
      kn2 = *(const short8*)(kp + 32);
      kn3 = *(const short8*)(kp + 48);
    }
    uint4 bw = *(const uint4*)(BpT + (size_t)t*1024);
    const signed char* bb = (const signed char*)&bw;
    short8 v00 = *(const short8*)(Vp + (size_t)l31*1152      + c0 +      hi*8);
    short8 v01 = *(const short8*)(Vp + (size_t)l31*1152      + c0 + 16 + hi*8);
    short8 v10 = *(const short8*)(Vp + (size_t)(32+l31)*1152 + c0 +      hi*8);
    short8 v11 = *(const short8*)(Vp + (size_t)(32+l31)*1152 + c0 + 16 + hi*8);
    f32x16 S = {};
    __builtin_amdgcn_s_setprio(1);
    S = mfma32(ka0, qf0, S);
    S = mfma32(ka1, qf1, S);
    S = mfma32(ka2, qf2, S);
    S = mfma32(ka3, qf3, S);
    __builtin_amdgcn_s_setprio(0);
    float p[16];
    float s0=0.f, s1=0.f, s2=0.f, s3=0.f;
    #pragma unroll
    for (int i=0;i<16;i++){
      float pv = __builtin_amdgcn_exp2f(fmaf(S[i], 0.18033688f, (float)bb[i]*0.015625f));
      p[i] = pv;
      if ((i&3)==0) s0 += pv; else if ((i&3)==1) s1 += pv;
      else if ((i&3)==2) s2 += pv; else s3 += pv;
    }
    lsum += (s0+s1)+(s2+s3);
    uint W00=cvtpk(p[0],p[1]),   W01=cvtpk(p[2],p[3]);
    uint W10=cvtpk(p[4],p[5]),   W11=cvtpk(p[6],p[7]);
    uint W20=cvtpk(p[8],p[9]),   W21=cvtpk(p[10],p[11]);
    uint W30=cvtpk(p[12],p[13]), W31=cvtpk(p[14],p[15]);
    uint x00 = (uint)__shfl_xor((int)(hi? W00 : W10), 32, 64);
    uint x01 = (uint)__shfl_xor((int)(hi? W01 : W11), 32, 64);
    uint x10 = (uint)__shfl_xor((int)(hi? W20 : W30), 32, 64);
    uint x11 = (uint)__shfl_xor((int)(hi? W21 : W31), 32, 64);
    union { uint u[4]; short8 v; } pf0, pf1;
    pf0.u[0] = hi ? x00 : W00;  pf0.u[1] = hi ? x01 : W01;
    pf0.u[2] = hi ? W10 : x00;  pf0.u[3] = hi ? W11 : x01;
    pf1.u[0] = hi ? x10 : W20;  pf1.u[1] = hi ? x11 : W21;
    pf1.u[2] = hi ? W30 : x10;  pf1.u[3] = hi ? W31 : x11;
    __builtin_amdgcn_s_setprio(1);
    O0 = mfma32(v00, pf0.v, O0);
    O0 = mfma32(v01, pf1.v, O0);
    O1 = mfma32(v10, pf0.v, O1);
    O1 = mfma32(v11, pf1.v, O1);
    __builtin_amdgcn_s_setprio(0);
  };
  for (int t=0;t<32;t+=2){
    step(kA0,kA1,kA2,kA3, kB0,kB1,kB2,kB3, t);
    step(kB0,kB1,kB2,kB3, kA0,kA1,kA2,kA3, t+1);
  }
  float inv = 1.f/(lsum + __shfl_xor(lsum, 32, 64));
  ushort* op = out + ((size_t)(b*1024 + r))*1152 + h*64;
  #pragma unroll
  for (int rq=0;rq<4;rq++)
    #pragma unroll
    for (int s=0;s<2;s++){
      int reg = rq*4 + s*2;
      uint w0 = cvtpk(O0[reg]*inv, O0[reg+1]*inv);
      uint w1 = cvtpk(O1[reg]*inv, O1[reg+1]*inv);
      int d = rq*8 + hi*4 + s*2;
      *(uint*)(op + d) = w0;
      *(uint*)(op + 32 + d) = w1;
    }
}

extern "C" void kernel_launch(void* const* d_in, const int* in_sizes, int n_in,
                              void* d_out, int out_size, void* d_ws, size_t ws_size,
                              hipStream_t stream)
{
  const float* x    = (const float*)d_in[0];
  const float* t    = (const float*)d_in[1];
  const float* ln1g = (const float*)d_in[2];
  const float* ln1b = (const float*)d_in[3];
  const float* qkvw = (const float*)d_in[4];
  const float* qkvb = (const float*)d_in[5];
  const float* timew= (const float*)d_in[6];
  const float* timeb= (const float*)d_in[7];
  const float* outw = (const float*)d_in[8];
  const float* outbv= (const float*)d_in[9];
  const float* Er   = (const float*)d_in[10];
  const float* ln2g = (const float*)d_in[11];
  const float* ln2b = (const float*)d_in[12];
  const float* ff1w = (const float*)d_in[13];
  const float* ff1b = (const float*)d_in[14];
  const float* ff2w = (const float*)d_in[15];
  const float* ff2b = (const float*)d_in[16];
  float* o = (float*)d_out;

  char* ws = (char*)d_ws;
  ushort* qkvw_t = (ushort*)(ws);              // [3072][1152]
  ushort* outw_t = (ushort*)(ws + 7077888);    // [1024][1152]
  ushort* ff1w_t = (ushort*)(ws + 9437184);    // [4096][1152]
  ushort* ff2w_t = (ushort*)(ws + 18874368);   // [1024][4224]
  ushort* er_b   = (ushort*)(ws + 27525120);   // [1024][64]
  float*  tq     = (float*) (ws + 27656192);   // [4][3072]
  ushort* bufA   = (ushort*)(ws + 27705344);   // [4096][1152]
  ushort* vt     = (ushort*)(ws + 37142528);   // [4096][1152]
  ushort* bufB   = (ushort*)(ws + 46579712);   // [4096][4224] (qkv at stride 3200 / ff1o at 4224)
  signed char* srelT = (signed char*)(ws + 81182720);  // [64][32][32][1024] tiled int8 (67.1 MB)

  wt_cvt<<<dim3(48,16),256,0,stream>>>(qkvw, qkvw_t, 1024, 3072, 1152);
  wt_cvt<<<dim3(16,16),256,0,stream>>>(outw, outw_t, 1024, 1024, 1152);
  wt_cvt<<<dim3(64,16),256,0,stream>>>(ff1w, ff1w_t, 1024, 4096, 1152);
  wt_cvt<<<dim3(16,64),256,0,stream>>>(ff2w, ff2w_t, 4096, 1024, 4224);
  cvt_f2b<<<256,256,0,stream>>>(Er, er_b, 65536);

  ln_rows<<<4096,256,0,stream>>>(x, ln1g, ln1b, bufA, 1152);
  tq_gemm2<<<48,256,0,stream>>>(t, timew, timeb, tq);
  gemm9<0,128><<<768,256,0,stream>>>(bufA, qkvw_t, qkvb, tq, bufB, nullptr,
                                     1024, 1152, 1152, 3200, 3072, 24);
  vt_k<<<dim3(16,64),256,0,stream>>>(bufB, vt);
  relskew8_v5<<<2048,256,0,stream>>>(bufB, er_b, srelT);
  attn11<<<512,256,0,stream>>>(bufB, srelT, vt, bufA);
  gemm9<1,64><<<512,256,0,stream>>>(bufA, outw_t, outbv, x, nullptr, o,
                                    1024, 1152, 1152, 1024, 1024, 16);
  ln_rows<<<4096,256,0,stream>>>(o, ln2g, ln2b, bufA, 1152);
  // FF1 at 256^2 tile: grid 16x16 = 256 WGs = exactly 1 per CU
  gemm10<2><<<256,512,0,stream>>>(bufA, ff1w_t, ff1b, nullptr, bufB, nullptr,
                                  1024, 1152, 1152, 4224, 0, 16);
  gemm9<1,64><<<512,256,0,stream>>>(bufB, ff2w_t, ff2b, o, nullptr, o,
                                    4096, 4224, 4224, 1024, 1024, 16);
}